// Round 21
// baseline (416.344 us; speedup 1.0000x reference)
//
#include <hip/hip_runtime.h>

#define HDIM 64

typedef _Float16 h2  __attribute__((ext_vector_type(2)));   // dot2 operand type
typedef __fp16   fp2 __attribute__((ext_vector_type(2)));   // cvt_pkrtz result type

#if defined(__has_builtin)
# if __has_builtin(__builtin_amdgcn_fdot2)
#  define FDOT2(a, b, c) __builtin_amdgcn_fdot2((a), (b), (c), false)
# endif
#endif
#ifndef FDOT2
__device__ __forceinline__ float fdot2_asm(h2 a, h2 b, float c) {
    float d;
    asm("v_dot2_f32_f16 %0, %1, %2, %3" : "=v"(d) : "v"(a), "v"(b), "v"(c));
    return d;
}
# define FDOT2(a, b, c) fdot2_asm((a), (b), (c))
#endif

__device__ __forceinline__ float fast_sigmoid(float v) {
    return __builtin_amdgcn_rcpf(1.0f + __builtin_amdgcn_exp2f(-1.442695041f * v));
}

__device__ __forceinline__ float fast_tanh(float v) {
    return 1.0f - 2.0f * __builtin_amdgcn_rcpf(1.0f + __builtin_amdgcn_exp2f(2.885390082f * v));
}

// 4-WAVE GATE-SPLIT, f16: 512 blocks x 256 threads = 2048 waves = 2/SIMD.
// Wave g owns gate g (i,f,g,o); lane l owns unit l's full K=64 gate-g row:
// 64 f16 = 32 packed uints, pinned. Per step/wave: 32 dot2 + ONE activation
// + stride-1 LDS exchange (abuf[gate][unit] — conflict-free, unlike r13's
// [unit][4] 12M-conflict layout) + 1 barrier + redundant cell + packed
// readlane broadcast (r19). The point vs r20: 2 waves/SIMD from DIFFERENT
// blocks (independent recurrences) interleave — the ~900cy serial tail that
// r20's 1-wave/SIMD config paid at full latency gets filled by the partner
// block's issue. r13's gate-split failure causes (64 scalar readlanes, bank
// conflicts, f32 budget) are all removed here.
// x staged via LDS in 64-step chunks (r6-validated).
__global__ __launch_bounds__(256)
__attribute__((amdgpu_waves_per_eu(2, 2)))
void bilstm_kernel(const float* __restrict__ x,
                   const float* __restrict__ w_ih_f,
                   const float* __restrict__ w_hh_f,
                   const float* __restrict__ b_ih_f,
                   const float* __restrict__ b_hh_f,
                   const float* __restrict__ w_ih_b,
                   const float* __restrict__ b_ih_b,
                   const float* __restrict__ b_hh_b,
                   const float* __restrict__ w_fc,
                   const float* __restrict__ b_fc,
                   float* __restrict__ out,
                   int T)
{
    const int b   = blockIdx.x;
    const int tid = threadIdx.x;
    const int g   = tid >> 6;      // gate id 0..3 (i,f,g,o)
    const int l   = tid & 63;      // unit index
    const int r   = (g << 6) | l;  // weight row

    __shared__ float abuf[2][4][HDIM];    // [parity][gate][unit] — stride-1 rows
    __shared__ float xstage[2][256];      // [parity][s*4+comp]

    // ---- pack the K=64 gate-g row into 32 h2 regs (stored as uint) ----
    unsigned wu[32];                      // [p] = packed {w[2p], w[2p+1]}
    {
        const float* row = w_hh_f + (size_t)r * HDIM;
        #pragma unroll
        for (int q = 0; q < 16; ++q) {
            float4 v = *(const float4*)(row + 4 * q);
            fp2 p0 = __builtin_amdgcn_cvt_pkrtz(v.x, v.y);
            fp2 p1 = __builtin_amdgcn_cvt_pkrtz(v.z, v.w);
            wu[2 * q + 0] = __builtin_bit_cast(unsigned, p0);
            wu[2 * q + 1] = __builtin_bit_cast(unsigned, p1);
        }
    }
    #define PIN_WU()                                                        \
        _Pragma("unroll")                                                   \
        for (int qq = 0; qq < 4; ++qq) {                                    \
            asm volatile("" : "+v"(wu[8*qq+0]), "+v"(wu[8*qq+1]),           \
                              "+v"(wu[8*qq+2]), "+v"(wu[8*qq+3]),           \
                              "+v"(wu[8*qq+4]), "+v"(wu[8*qq+5]),           \
                              "+v"(wu[8*qq+6]), "+v"(wu[8*qq+7]));          \
        }
    PIN_WU()

    float4 wxf = *(const float4*)(w_ih_f + (size_t)r * 4);
    float  bz  = b_ih_f[r] + b_hh_f[r];
    asm volatile("" : "+v"(wxf.x), "+v"(wxf.y), "+v"(wxf.z), "+v"(wxf.w), "+v"(bz));

    // wave-uniform activation selector: sigmoid for g!=2, tanh for g==2
    const float sc = (g == 2) ? 2.885390082f : -1.442695041f;

    const float* xb = x + (size_t)b * T * 4;
    const int lim = T * 4 - 1;

    // prologue: stage chunk 0
    {
        int idx = tid;  if (idx > lim) idx = lim;
        xstage[0][tid] = xb[idx];
    }
    __syncthreads();

    // h broadcast state: 32 packed f16 pairs (uniform after readlane)
    unsigned hs[32];
    #pragma unroll
    for (int k = 0; k < 32; ++k) hs[k] = 0u;
    float c = 0.0f, h = 0.0f;

    #define W2(pp) __builtin_bit_cast(h2, wu[pp])
    #define H2(u)  __builtin_bit_cast(h2, (u))

    const int NCH = (T + 63) >> 6;

    for (int ch = 0; ch < NCH; ++ch) {
        const int nst = ((T - (ch << 6)) < 64) ? (T - (ch << 6)) : 64;
        const float* xs = xstage[ch & 1];
        const bool more = (ch + 1 < NCH);
        float xnf = 0.0f;
        if (more) {
            int idx = ((ch + 1) << 8) + tid;  if (idx > lim) idx = lim;
            xnf = xb[idx];   // drained at first in-chunk barrier (once / 64 steps)
        }

        #define STEP(S, P) do {                                              \
            const float4 xt = *(const float4*)(&xs[(S) << 2]);               \
            float aA = bz, aB = 0.0f;                                        \
            _Pragma("unroll")                                                \
            for (int q = 0; q < 8; ++q) {                                    \
                aA = FDOT2(W2(4*q+0), H2(hs[4*q+0]), aA);                    \
                aB = FDOT2(W2(4*q+1), H2(hs[4*q+1]), aB);                    \
                aA = FDOT2(W2(4*q+2), H2(hs[4*q+2]), aA);                    \
                aB = FDOT2(W2(4*q+3), H2(hs[4*q+3]), aB);                    \
            }                                                                \
            const float A = aA + aB + (wxf.x * xt.x + wxf.y * xt.y           \
                                     + wxf.z * xt.z + wxf.w * xt.w);         \
            const float e  = __builtin_amdgcn_exp2f(sc * A);                 \
            const float rr = __builtin_amdgcn_rcpf(1.0f + e);                \
            const float v  = (g == 2) ? 1.0f - 2.0f * rr : rr;               \
            abuf[P][g][l] = v;                                               \
            __syncthreads();                                                 \
            const float gi = abuf[P][0][l];                                  \
            const float gf = abuf[P][1][l];                                  \
            const float gg = abuf[P][2][l];                                  \
            const float go = abuf[P][3][l];                                  \
            c = gf * c + gi * gg;                                            \
            h = go * fast_tanh(c);                                           \
            const unsigned hr = __builtin_bit_cast(unsigned,                 \
                                    __builtin_amdgcn_cvt_pkrtz(h, h));       \
            const unsigned nb = (unsigned)__builtin_amdgcn_update_dpp(       \
                                    (int)hr, (int)hr, 0xB1, 0xF, 0xF, true); \
            const unsigned pk = (hr & 0xffffu) | (nb << 16);                 \
            _Pragma("unroll")                                                \
            for (int k = 0; k < 32; ++k)                                     \
                hs[k] = (unsigned)__builtin_amdgcn_readlane((int)pk, 2 * k); \
        } while (0)

        for (int s = 0; s < nst; s += 2) {
            STEP(s,     0);
            STEP(s + 1, 1);
        }
        #undef STEP

        if (more) {
            xstage[(ch + 1) & 1][tid] = xnf;
            __syncthreads();
        }
    }

    #undef W2
    #undef H2
    #undef PIN_WU

    // ---- epilogue: wave 0 — backward cell + fc + sigmoid ----
    if (g == 0) {
        // backward-direction single cell from zero state at x[:, T-1]
        // (w_hh_b never multiplies nonzero state)
        float4 xl = *(const float4*)(xb + 4 * (T - 1));
        float gb[4];
        #pragma unroll
        for (int jj = 0; jj < 4; ++jj) {
            const int rr2 = (jj << 6) | l;
            float4 wb = *(const float4*)(w_ih_b + (size_t)rr2 * 4);
            gb[jj] = b_ih_b[rr2] + b_hh_b[rr2]
                   + wb.x * xl.x + wb.y * xl.y + wb.z * xl.z + wb.w * xl.w;
        }
        const float ib  = fast_sigmoid(gb[0]);
        const float ggb = fast_tanh(gb[2]);
        const float ob  = fast_sigmoid(gb[3]);
        const float cb  = ib * ggb;
        const float hbk = ob * fast_tanh(cb);

        // h register holds the final forward h for unit l (computed redundantly)
        float p = w_fc[l] * h + w_fc[HDIM + l] * hbk;
        #pragma unroll
        for (int off = 32; off; off >>= 1) p += __shfl_xor(p, off);

        if (l == 0) out[b] = fast_sigmoid(p + b_fc[0]);
    }
}

extern "C" void kernel_launch(void* const* d_in, const int* in_sizes, int n_in,
                              void* d_out, int out_size, void* d_ws, size_t ws_size,
                              hipStream_t stream) {
    const float* x      = (const float*)d_in[0];
    const float* w_ih_f = (const float*)d_in[1];
    const float* w_hh_f = (const float*)d_in[2];
    const float* b_ih_f = (const float*)d_in[3];
    const float* b_hh_f = (const float*)d_in[4];
    const float* w_ih_b = (const float*)d_in[5];
    // d_in[6] = w_hh_b — unused (backward cell starts from zero state)
    const float* b_ih_b = (const float*)d_in[7];
    const float* b_hh_b = (const float*)d_in[8];
    const float* w_fc   = (const float*)d_in[9];
    const float* b_fc   = (const float*)d_in[10];
    float* out = (float*)d_out;

    const int B = out_size;                 // 512
    const int T = in_sizes[0] / (B * 4);    // 1000

    bilstm_kernel<<<dim3(B), dim3(256), 0, stream>>>(
        x, w_ih_f, w_hh_f, b_ih_f, b_hh_f,
        w_ih_b, b_ih_b, b_hh_b, w_fc, b_fc, out, T);
}